// Round 4
// baseline (155.372 us; speedup 1.0000x reference)
//
#include <hip/hip_runtime.h>

#define IMG_W 512
#define IMG_H 512
#define PLANE_PX (IMG_W * IMG_H)
#define N_ELEMS (48 * PLANE_PX)
#define NTHREADS 256
#define NBLK 3072                  // 12288 waves: 48 planes x 32 bands x 8 strips
#define NWAVES (NBLK * 4)

// 2*C1 and 2*C2 (the 0.25 scale factors cancel in num/den)
#define C1x2 2.0e-4f
#define C2x2 1.8e-3f

typedef _Float16 h2 __attribute__((ext_vector_type(2)));
typedef _Float16 h8 __attribute__((ext_vector_type(8)));
typedef float f32x4 __attribute__((ext_vector_type(4)));
typedef __fp16 fp16v2 __attribute__((ext_vector_type(2)));

__device__ __forceinline__ unsigned int h2bits(h2 v) {
    union { h2 h; unsigned int u; } c; c.h = v; return c.u;
}
// v_cvt_pkrtz_f16_f32 returns __fp16x2; bit-cast to _Float16x2 (same layout).
__device__ __forceinline__ h2 pkrtz(float x, float y) {
    union { fp16v2 f; h2 h; } c;
    c.f = __builtin_amdgcn_cvt_pkrtz(x, y);
    return c.h;
}

union FrU { h8 h; unsigned u[4]; h2 p[4]; };

__global__ void __launch_bounds__(NTHREADS, 4) ssim_main(
    const float* __restrict__ img1, const float* __restrict__ img2,
    float* __restrict__ partials)
{
    // Barrier-free, LDS-free design: each WAVE independently computes a
    // 16-row x 64-col output strip as 4 sub-tiles of 16x16.
    // Per sub-tile: vertical conv = 2 MFMAs/signal over a 32-col window with
    // an INTERLEAVED column->m mapping phi_T(m) = (m>>2)*8 + (m&3) + 4T,
    // chosen so each lane's vertical D output (m-quads khi*4+i -> cols
    // khi*8+i+4T) is exactly the 8 staged cols its horizontal B-fragment
    // needs (k = khi*8+0..7). Vertical->horizontal handoff is pure-register
    // (pkrtz pairs), no LDS, no shuffles, no __syncthreads.
    const int tid = threadIdx.x;
    const int lane = tid & 63;
    const int wv = tid >> 6;
    const int nr = lane & 15;
    const int khi = lane >> 4;

    // XCD swizzle: XCD (blockIdx&7) owns 6 contiguous planes.
    const int bswz = (blockIdx.x & 7) * (NBLK / 8) + (blockIdx.x >> 3);
    const int wid = bswz * 4 + wv;               // [0, 12288)
    const int pl = wid >> 8;                     // 256 waves/plane
    const int r = wid & 255;
    const int oy0 = (r >> 3) * 16;               // band [0,512) step 16
    const int sx0 = (r & 7) * 64;                // strip of 64 out cols
    const float* pa = img1 + (size_t)pl * PLANE_PX;
    const float* pb = img2 + (size_t)pl * PLANE_PX;

    // Gaussian band fragments (built once; lanes >= 11 hold 0):
    //   afv (vertical B):   B[k][n] = G[k-n]   -> t0 = khi*8+2w - nr
    //   afh (horizontal A): A[m][k] = G[k-m-3] -> t0 = khi*8+2w - nr - 3
    //   (window start wx = ox0-8, so k-m-3 in [0,10] <=> tap index)
    int sidx = min(lane, 10 - lane);             // < 0 for lane > 10
    unsigned gvb = 0u;
    gvb = (sidx == 0) ? 0x1436u : gvb;           // f16 bits of G[0]
    gvb = (sidx == 1) ? 0x1FC8u : gvb;
    gvb = (sidx == 2) ? 0x289Cu : gvb;
    gvb = (sidx == 3) ? 0x2F00u : gvb;
    gvb = (sidx == 4) ? 0x32D1u : gvb;
    gvb = (sidx == 5) ? 0x3442u : gvb;           // f16 bits of G[5]
    FrU afv, afh;
#pragma unroll
    for (int w = 0; w < 4; ++w) {
        int t0 = khi * 8 + 2 * w - nr;
        unsigned lo = (unsigned)__shfl((int)gvb, t0 & 63, 64);
        unsigned hi = (unsigned)__shfl((int)gvb, (t0 + 1) & 63, 64);
        afv.u[w] = (lo & 0xFFFFu) | (hi << 16);
        unsigned lo2 = (unsigned)__shfl((int)gvb, (t0 - 3) & 63, 64);
        unsigned hi2 = (unsigned)__shfl((int)gvb, (t0 - 2) & 63, 64);
        afh.u[w] = (lo2 & 0xFFFFu) | (hi2 << 16);
    }

    const int ry0 = oy0 - 5;
    const int ryb = ry0 + khi * 8;               // this lane's first staged row
    // k-slots 26..31 are out-of-band (G=0): khi==3 lanes only load j<2.
    const bool fastY = (ry0 >= 0) && (ry0 + 25 < IMG_H);     // wave-uniform
    const int colo = ((nr >> 2) << 3) + (nr & 3);            // phi(m=nr), T=0

    const f32x4 z = {0.f, 0.f, 0.f, 0.f};
    float local = 0.f;

#pragma unroll 1
    for (int mg = 0; mg < 4; ++mg) {
        const int ox0 = sx0 + mg * 16;
        const int wx = ox0 - 8;                  // 32-col staging window
        const int c0 = wx + colo;                // tile0 col for this lane
        const int c1 = c0 + 4;                   // tile1 col
        const bool edgeC = (wx < 0) || (wx + 32 > IMG_W);    // wave-uniform
        const int cc0 = min(max(c0, 0), IMG_W - 1);
        const int cc1 = min(max(c1, 0), IMG_W - 1);

        // ---- loads: 8 rows x 2 cols x 2 images (khi==3: only 2 rows) ----
        float a0[8], b0[8], a1[8], b1[8];
#pragma unroll
        for (int j = 0; j < 8; ++j) { a0[j] = 0.f; b0[j] = 0.f; a1[j] = 0.f; b1[j] = 0.f; }
#define LOADJ_FAST(j) { \
            a0[j] = qa[(j) * IMG_W + cc0]; b0[j] = qb[(j) * IMG_W + cc0]; \
            a1[j] = qa[(j) * IMG_W + cc1]; b1[j] = qb[(j) * IMG_W + cc1]; }
#define LOADJ_EDGE(j) { \
            int ry = ryb + (j); \
            int ryc = min(max(ry, 0), IMG_H - 1); \
            float rm = ((unsigned)ry < (unsigned)IMG_H) ? 1.f : 0.f; \
            a0[j] = pa[(size_t)ryc * IMG_W + cc0] * rm; \
            b0[j] = pb[(size_t)ryc * IMG_W + cc0] * rm; \
            a1[j] = pa[(size_t)ryc * IMG_W + cc1] * rm; \
            b1[j] = pb[(size_t)ryc * IMG_W + cc1] * rm; }
        if (fastY) {
            const float* qa = pa + (size_t)ryb * IMG_W;
            const float* qb = pb + (size_t)ryb * IMG_W;
            LOADJ_FAST(0) LOADJ_FAST(1)
            if (khi != 3) {
#pragma unroll
                for (int j = 2; j < 8; ++j) LOADJ_FAST(j)
            }
        } else {
            LOADJ_EDGE(0) LOADJ_EDGE(1)
            if (khi != 3) {
#pragma unroll
                for (int j = 2; j < 8; ++j) LOADJ_EDGE(j)
            }
        }
#undef LOADJ_FAST
#undef LOADJ_EDGE

        // ---- (s,d) f16 fragments for both tiles ----
        FrU FS0, FD0, FS1, FD1;
#pragma unroll
        for (int w = 0; w < 4; ++w) {
            FS0.p[w] = pkrtz(a0[2 * w] + b0[2 * w], a0[2 * w + 1] + b0[2 * w + 1]);
            FD0.p[w] = pkrtz(a0[2 * w] - b0[2 * w], a0[2 * w + 1] - b0[2 * w + 1]);
            FS1.p[w] = pkrtz(a1[2 * w] + b1[2 * w], a1[2 * w + 1] + b1[2 * w + 1]);
            FD1.p[w] = pkrtz(a1[2 * w] - b1[2 * w], a1[2 * w + 1] - b1[2 * w + 1]);
        }
        if (edgeC) {   // zero-pad OOB columns (per-lane col, wave-uniform branch)
            const _Float16 m0 = ((unsigned)c0 < (unsigned)IMG_W) ? (_Float16)1.f : (_Float16)0.f;
            const _Float16 m1 = ((unsigned)c1 < (unsigned)IMG_W) ? (_Float16)1.f : (_Float16)0.f;
            const h2 m0v = {m0, m0}, m1v = {m1, m1};
#pragma unroll
            for (int w = 0; w < 4; ++w) {
                FS0.p[w] *= m0v; FD0.p[w] *= m0v;
                FS1.p[w] *= m1v; FD1.p[w] *= m1v;
            }
        }
        FrU FSS0, FDD0, FSS1, FDD1;
#pragma unroll
        for (int w = 0; w < 4; ++w) {
            FSS0.p[w] = FS0.p[w] * FS0.p[w];     // v_pk_mul_f16
            FDD0.p[w] = FD0.p[w] * FD0.p[w];
            FSS1.p[w] = FS1.p[w] * FS1.p[w];
            FDD1.p[w] = FD1.p[w] * FD1.p[w];
        }

        // ---- vertical conv: mfma(A=signal[m=col][k=row], B=afv) ----
        // D: r = khi*4+i -> col khi*8+i+4T, c = lane&15 -> out row. (R2-verified)
        f32x4 oS0  = __builtin_amdgcn_mfma_f32_16x16x32_f16(FS0.h,  afv.h, z, 0, 0, 0);
        f32x4 oD0  = __builtin_amdgcn_mfma_f32_16x16x32_f16(FD0.h,  afv.h, z, 0, 0, 0);
        f32x4 oSS0 = __builtin_amdgcn_mfma_f32_16x16x32_f16(FSS0.h, afv.h, z, 0, 0, 0);
        f32x4 oDD0 = __builtin_amdgcn_mfma_f32_16x16x32_f16(FDD0.h, afv.h, z, 0, 0, 0);
        f32x4 oS1  = __builtin_amdgcn_mfma_f32_16x16x32_f16(FS1.h,  afv.h, z, 0, 0, 0);
        f32x4 oD1  = __builtin_amdgcn_mfma_f32_16x16x32_f16(FD1.h,  afv.h, z, 0, 0, 0);
        f32x4 oSS1 = __builtin_amdgcn_mfma_f32_16x16x32_f16(FSS1.h, afv.h, z, 0, 0, 0);
        f32x4 oDD1 = __builtin_amdgcn_mfma_f32_16x16x32_f16(FDD1.h, afv.h, z, 0, 0, 0);

        // ---- pack D -> horizontal B-fragments (pure register handoff) ----
        // bX.u[w]: k = khi*8 + 2w,2w+1; tile0 supplies w=0,1; tile1 w=2,3.
        FrU bS, bD, bSS, bDD;
        bS.u[0]  = h2bits(pkrtz(oS0[0],  oS0[1]));  bS.u[1]  = h2bits(pkrtz(oS0[2],  oS0[3]));
        bS.u[2]  = h2bits(pkrtz(oS1[0],  oS1[1]));  bS.u[3]  = h2bits(pkrtz(oS1[2],  oS1[3]));
        bD.u[0]  = h2bits(pkrtz(oD0[0],  oD0[1]));  bD.u[1]  = h2bits(pkrtz(oD0[2],  oD0[3]));
        bD.u[2]  = h2bits(pkrtz(oD1[0],  oD1[1]));  bD.u[3]  = h2bits(pkrtz(oD1[2],  oD1[3]));
        bSS.u[0] = h2bits(pkrtz(oSS0[0], oSS0[1])); bSS.u[1] = h2bits(pkrtz(oSS0[2], oSS0[3]));
        bSS.u[2] = h2bits(pkrtz(oSS1[0], oSS1[1])); bSS.u[3] = h2bits(pkrtz(oSS1[2], oSS1[3]));
        bDD.u[0] = h2bits(pkrtz(oDD0[0], oDD0[1])); bDD.u[1] = h2bits(pkrtz(oDD0[2], oDD0[3]));
        bDD.u[2] = h2bits(pkrtz(oDD1[0], oDD1[1])); bDD.u[3] = h2bits(pkrtz(oDD1[2], oDD1[3]));

        // ---- horizontal conv: mfma(A=afh, B=planes) (R1/R2-verified layout) ----
        f32x4 aS  = __builtin_amdgcn_mfma_f32_16x16x32_f16(afh.h, bS.h,  z, 0, 0, 0);
        f32x4 aD  = __builtin_amdgcn_mfma_f32_16x16x32_f16(afh.h, bD.h,  z, 0, 0, 0);
        f32x4 aSS = __builtin_amdgcn_mfma_f32_16x16x32_f16(afh.h, bSS.h, z, 0, 0, 0);
        f32x4 aDD = __builtin_amdgcn_mfma_f32_16x16x32_f16(afh.h, bDD.h, z, 0, 0, 0);

        // ---- SSIM epilogue: every px valid (512 % 16 == 0, no partial tiles)
#pragma unroll
        for (int i = 0; i < 4; ++i) {
            float cs = aS[i], cd = aD[i], css = aSS[i], cdd = aDD[i];
            float Pq = cs * cs, Qq = cd * cd;
            float U = Pq - Qq;                   // 4*mu1*mu2
            float V = Pq + Qq;                   // 2*(mu1^2+mu2^2)
            float num = (U + C1x2) * ((css - cdd) - U + C2x2);
            float den = (V + C1x2) * ((css + cdd) - V + C2x2);
            local += num * __builtin_amdgcn_rcpf(den);
        }
    }

    // ---- wave reduction -> one partial per wave (no LDS, no barrier) ----
#pragma unroll
    for (int off = 32; off > 0; off >>= 1) local += __shfl_down(local, off, 64);
    if (lane == 0) partials[wid] = local;
}

__global__ void ssim_final(const float* __restrict__ partials,
                           float* __restrict__ out)
{
    __shared__ float wp[4];
    const int tid = threadIdx.x;
    const float4* p4 = (const float4*)partials;  // 12288/4 = 3072 float4
    float s = 0.f;
    for (int i = tid; i < NWAVES / 4; i += NTHREADS) {
        float4 v = p4[i];
        s += (v.x + v.y) + (v.z + v.w);
    }
#pragma unroll
    for (int off = 32; off > 0; off >>= 1) s += __shfl_down(s, off, 64);
    if ((tid & 63) == 0) wp[tid >> 6] = s;
    __syncthreads();
    if (tid == 0)
        out[0] = 1.0f - (wp[0] + wp[1] + wp[2] + wp[3]) * (1.0f / (float)N_ELEMS);
}

extern "C" void kernel_launch(void* const* d_in, const int* in_sizes, int n_in,
                              void* d_out, int out_size, void* d_ws, size_t ws_size,
                              hipStream_t stream) {
    const float* img1 = (const float*)d_in[0];
    const float* img2 = (const float*)d_in[1];
    float* out = (float*)d_out;
    float* partials = (float*)d_ws;     // NWAVES floats = 49.2 KB

    ssim_main<<<NBLK, NTHREADS, 0, stream>>>(img1, img2, partials);
    ssim_final<<<1, NTHREADS, 0, stream>>>(partials, out);
}

// Round 5
// 133.804 us; speedup vs baseline: 1.1612x; 1.1612x over previous
//
#include <hip/hip_runtime.h>

#define IMG_W 512
#define IMG_H 512
#define PLANE_PX (IMG_W * IMG_H)
#define N_ELEMS (48 * PLANE_PX)
#define NTHREADS 256
#define TILEW 48
#define NCT 11                  // 10 full col-tiles + 1 partial (32 cols)
#define NBANDS 16               // 32-row bands
#define NBLK (48 * NBANDS * NCT)   // 8448

// 2*C1 and 2*C2 (the 0.25 scale factors cancel in num/den)
#define C1x2 2.0e-4f
#define C2x2 1.8e-3f

typedef _Float16 h2 __attribute__((ext_vector_type(2)));
typedef _Float16 h8 __attribute__((ext_vector_type(8)));
typedef float f32x4 __attribute__((ext_vector_type(4)));
typedef __fp16 fp16v2 __attribute__((ext_vector_type(2)));

// Packed f16 FMA (v_pk_fma_f16).
__device__ __forceinline__ h2 h2fma(_Float16 w, h2 v, h2 acc) {
    h2 wv = {w, w};
    return __builtin_elementwise_fma(wv, v, acc);
}
__device__ __forceinline__ unsigned int h2bits(h2 v) {
    union { h2 h; unsigned int u; } c; c.h = v; return c.u;
}
// v_cvt_pkrtz_f16_f32 returns __fp16x2; bit-cast to _Float16x2 (same layout).
__device__ __forceinline__ h2 pkrtz(float x, float y) {
    union { fp16v2 f; h2 h; } c;
    c.f = __builtin_amdgcn_cvt_pkrtz(x, y);
    return c.h;
}

__global__ void __launch_bounds__(NTHREADS, 8) ssim_main(
    const float* __restrict__ img1, const float* __restrict__ img2,
    float* __restrict__ partials)
{
    // R1 structure (best measured: 41.4us) at HALF the band height:
    // 32-row bands -> LDS 16 KiB -> 8 blocks/CU (thread-slot cap), the
    // configuration under which R0 actually achieved 63% residency.
    // Packed f16 planes: R[row][col] = {(cs,cd),(css,cdd)}, 32x64 uint2.
    // Col XOR swizzle: physical = logical ^ ((row&7)<<1) (bit0 untouched ->
    // uint2 pairs stay contiguous for the b128 reads in Phase B).
    __shared__ __align__(16) uint2 R[32 * 64];   // 16384 B

    // Gaussian window (f16 taps for conv).
    constexpr _Float16 Gh[11] = {
        (_Float16)0.00102838f, (_Float16)0.00759876f, (_Float16)0.03600077f,
        (_Float16)0.10936070f, (_Float16)0.21300553f, (_Float16)0.26601173f,
        (_Float16)0.21300553f, (_Float16)0.10936070f, (_Float16)0.03600077f,
        (_Float16)0.00759876f, (_Float16)0.00102838f
    };

    const int tid = threadIdx.x;
    const int lane = tid & 63;
    const int wv = tid >> 6;

    // Work decode + XCD swizzle: XCD (blockIdx&7) owns 6 contiguous planes.
    const int xcd = blockIdx.x & 7;
    const int idx = blockIdx.x >> 3;             // [0,1056)
    const int pl = xcd * 6 + idx / 176;          // 176 = 16 bands * 11 ct
    const int t = idx % 176;
    const int band = t / 11;                     // y-band [0,16), 32 rows
    const int ct = t - band * 11;                // col-tile [0,11)
    const int tx0 = ct * TILEW;
    const int ty0 = band * 32;
    const float* pa = img1 + (size_t)pl * PLANE_PX;
    const float* pb = img2 + (size_t)pl * PLANE_PX;

    // ================= Phase A: vertical conv, lane = staged column =========
    // 4 waves x 8 output rows each; each stages 18 rows x 64 coalesced cols.
    const int c = lane;                          // staged col
    const int g = wv;                            // wave = row-group
    const int gx = tx0 - 5 + c;
    const int cgx = min(max(gx, 0), IMG_W - 1);
    const int ry0 = ty0 + g * 8 - 5;

    float av[18], bv[18];
    const bool intY = (ry0 >= 0) && (ry0 + 18 <= IMG_H);     // wave-uniform
    if (intY) {
        const float* qa = pa + (size_t)ry0 * IMG_W + cgx;
        const float* qb = pb + (size_t)ry0 * IMG_W + cgx;
#pragma unroll
        for (int j = 0; j < 18; ++j) {
            av[j] = qa[j * IMG_W];
            bv[j] = qb[j * IMG_W];
        }
    } else {
#pragma unroll
        for (int j = 0; j < 18; ++j) {
            int ry = ry0 + j;
            int ryc = min(max(ry, 0), IMG_H - 1);
            float rm = ((unsigned)ry < (unsigned)IMG_H) ? 1.f : 0.f;
            av[j] = pa[(size_t)ryc * IMG_W + cgx] * rm;
            bv[j] = pb[(size_t)ryc * IMG_W + cgx] * rm;
        }
    }

    h2 asd[8], asq[8];
#pragma unroll
    for (int k = 0; k < 8; ++k) { asd[k] = (h2)(_Float16)0; asq[k] = (h2)(_Float16)0; }
#pragma unroll
    for (int j = 0; j < 18; ++j) {
        // (s,d) packed to f16 in ONE inst (v_cvt_pkrtz_f16_f32).
        h2 sd = pkrtz(av[j] + bv[j], av[j] - bv[j]);
        h2 sq = sd * sd;                         // v_pk_mul_f16
#pragma unroll
        for (int k = 0; k < 8; ++k) {
            int tt = j - k;
            if (tt >= 0 && tt < 11) {            // folds at compile time
                asd[k] = h2fma(Gh[tt], sd, asd[k]);
                asq[k] = h2fma(Gh[tt], sq, asq[k]);
            }
        }
    }

    // Column mask only needed for the edge col-tiles (block-uniform branch).
    if (ct == 0 || ct == NCT - 1) {
        const _Float16 ml = ((unsigned)gx < (unsigned)IMG_W) ? (_Float16)1.f
                                                             : (_Float16)0.f;
        const h2 mlv = {ml, ml};
#pragma unroll
        for (int k = 0; k < 8; ++k) { asd[k] = asd[k] * mlv; asq[k] = asq[k] * mlv; }
    }
#pragma unroll
    for (int k = 0; k < 8; ++k) {
        const int row = g * 8 + k;               // row&7 == k (g*8 % 8 == 0)
        const int sc = c ^ ((k & 7) << 1);       // swizzled physical col
        R[row * 64 + sc] = make_uint2(h2bits(asd[k]), h2bits(asq[k]));
    }
    __syncthreads();

    // ================= Phase B: horizontal conv via MFMA + SSIM =============
    // D[m][n] = sum_k A[m][k]*B[k][n], one mfma_f32_16x16x32_f16 per signal:
    //   m = output col in 16-col group, k = staged col in 32-window (band
    //   G[k-m], k-m in [0,11), max k = 25 < 32), n = image row slot.
    // A operand (lane l): m = l&15, k = (l>>4)*8 + j  -> constant band frag.
    // B operand (lane l): n = l&15, k = (l>>4)*8 + j  -> 4x ds_read_b128.
    // D layout: n = l&15, m = (l>>4)*4 + reg -> f32, no cvts.
    // 32 rows = 2 MFMA row-sets; waves {0,1}->set 0, {2,3}->set 1.
    // Within a pair: even wave owns mg {0,1}, odd wave owns mg {2}.
    const int nrow = lane & 15;
    const int khi = lane >> 4;
    const int rset = wv >> 1;
    const int row_lds = rset * 16 + nrow;
    const int swz = (nrow & 7) << 1;             // row_lds&7 == nrow&7
    const uint2* Rrow = R + row_lds * 64;

    // Constant Gaussian band A-fragment (symmetric-tap select + 8 shuffles;
    // lanes >= 11 hold 0 so out-of-band taps are 0).
    int sidx = min(lane, 10 - lane);             // < 0 for lane > 10
    unsigned gvb = 0u;
    gvb = (sidx == 0) ? 0x1436u : gvb;           // f16 bits of G[0]
    gvb = (sidx == 1) ? 0x1FC8u : gvb;
    gvb = (sidx == 2) ? 0x289Cu : gvb;
    gvb = (sidx == 3) ? 0x2F00u : gvb;
    gvb = (sidx == 4) ? 0x32D1u : gvb;
    gvb = (sidx == 5) ? 0x3442u : gvb;           // f16 bits of G[5]
    union { h8 h; unsigned u[4]; } af;
#pragma unroll
    for (int w = 0; w < 4; ++w) {
        int t0 = khi * 8 + 2 * w - nrow;
        unsigned lo = (unsigned)__shfl((int)gvb, t0 & 63, 64);
        unsigned hi = (unsigned)__shfl((int)gvb, (t0 + 1) & 63, 64);
        af.u[w] = (lo & 0xFFFFu) | (hi << 16);
    }

    const f32x4 z = {0.f, 0.f, 0.f, 0.f};
    float local = 0.f;
#pragma unroll
    for (int mg = 0; mg < 3; ++mg) {
        // ownership: waves 0,2 take mg 0,1; waves 1,3 take mg 2.
        if (((mg >> 1) == (wv & 1)) && (tx0 + mg * 16 < IMG_W)) {
            const int cb = mg * 16 + khi * 8;    // even; swz even -> pairs stay
            const uint4 q0 = *(const uint4*)&Rrow[(cb + 0) ^ swz];
            const uint4 q1 = *(const uint4*)&Rrow[(cb + 2) ^ swz];
            const uint4 q2 = *(const uint4*)&Rrow[(cb + 4) ^ swz];
            const uint4 q3 = *(const uint4*)&Rrow[(cb + 6) ^ swz];

            // De-interleave packed {(s,d),(ss,dd)} into 4 per-signal frags.
            union { h8 h; unsigned u[4]; } fs, fd, fss, fdd;
            fs.u[0]  = (q0.x & 0xFFFFu) | (q0.z << 16);
            fs.u[1]  = (q1.x & 0xFFFFu) | (q1.z << 16);
            fs.u[2]  = (q2.x & 0xFFFFu) | (q2.z << 16);
            fs.u[3]  = (q3.x & 0xFFFFu) | (q3.z << 16);
            fd.u[0]  = (q0.x >> 16) | (q0.z & 0xFFFF0000u);
            fd.u[1]  = (q1.x >> 16) | (q1.z & 0xFFFF0000u);
            fd.u[2]  = (q2.x >> 16) | (q2.z & 0xFFFF0000u);
            fd.u[3]  = (q3.x >> 16) | (q3.z & 0xFFFF0000u);
            fss.u[0] = (q0.y & 0xFFFFu) | (q0.w << 16);
            fss.u[1] = (q1.y & 0xFFFFu) | (q1.w << 16);
            fss.u[2] = (q2.y & 0xFFFFu) | (q2.w << 16);
            fss.u[3] = (q3.y & 0xFFFFu) | (q3.w << 16);
            fdd.u[0] = (q0.y >> 16) | (q0.w & 0xFFFF0000u);
            fdd.u[1] = (q1.y >> 16) | (q1.w & 0xFFFF0000u);
            fdd.u[2] = (q2.y >> 16) | (q2.w & 0xFFFF0000u);
            fdd.u[3] = (q3.y >> 16) | (q3.w & 0xFFFF0000u);

            f32x4 aS  = __builtin_amdgcn_mfma_f32_16x16x32_f16(af.h, fs.h,  z, 0, 0, 0);
            f32x4 aD  = __builtin_amdgcn_mfma_f32_16x16x32_f16(af.h, fd.h,  z, 0, 0, 0);
            f32x4 aSS = __builtin_amdgcn_mfma_f32_16x16x32_f16(af.h, fss.h, z, 0, 0, 0);
            f32x4 aDD = __builtin_amdgcn_mfma_f32_16x16x32_f16(af.h, fdd.h, z, 0, 0, 0);

            // num/den share the 0.25 factor -> cancelled; constants are 2*C.
#pragma unroll
            for (int i = 0; i < 4; ++i) {
                float cs = aS[i], cd = aD[i], css = aSS[i], cdd = aDD[i];
                float Pq = cs * cs, Qq = cd * cd;
                float U = Pq - Qq;               // 4*mu1*mu2
                float V = Pq + Qq;               // 2*(mu1^2+mu2^2)
                float num = (U + C1x2) * ((css - cdd) - U + C2x2);
                float den = (V + C1x2) * ((css + cdd) - V + C2x2);
                local += num * __builtin_amdgcn_rcpf(den);
            }
        }
    }

    // ================= Block reduction -> one partial ========================
#pragma unroll
    for (int off = 32; off > 0; off >>= 1) local += __shfl_down(local, off, 64);
    __syncthreads();                             // all R reads done: safe alias
    float* wp = (float*)R;
    if (lane == 0) wp[wv] = local;
    __syncthreads();
    if (tid == 0)
        partials[blockIdx.x] = wp[0] + wp[1] + wp[2] + wp[3];
}

__global__ void ssim_final(const float* __restrict__ partials,
                           float* __restrict__ out)
{
    __shared__ float wp[4];
    const int tid = threadIdx.x;
    const float4* p4 = (const float4*)partials;  // 8448/4 = 2112 float4
    float s = 0.f;
    for (int i = tid; i < NBLK / 4; i += NTHREADS) {
        float4 v = p4[i];
        s += (v.x + v.y) + (v.z + v.w);
    }
#pragma unroll
    for (int off = 32; off > 0; off >>= 1) s += __shfl_down(s, off, 64);
    if ((tid & 63) == 0) wp[tid >> 6] = s;
    __syncthreads();
    if (tid == 0)
        out[0] = 1.0f - (wp[0] + wp[1] + wp[2] + wp[3]) * (1.0f / (float)N_ELEMS);
}

extern "C" void kernel_launch(void* const* d_in, const int* in_sizes, int n_in,
                              void* d_out, int out_size, void* d_ws, size_t ws_size,
                              hipStream_t stream) {
    const float* img1 = (const float*)d_in[0];
    const float* img2 = (const float*)d_in[1];
    float* out = (float*)d_out;
    float* partials = (float*)d_ws;     // NBLK floats = 33.8 KB

    ssim_main<<<NBLK, NTHREADS, 0, stream>>>(img1, img2, partials);
    ssim_final<<<1, NTHREADS, 0, stream>>>(partials, out);
}

// Round 7
// 121.195 us; speedup vs baseline: 1.2820x; 1.1040x over previous
//
#include <hip/hip_runtime.h>

#define IMG_W 512
#define IMG_H 512
#define PLANE_PX (IMG_W * IMG_H)
#define N_ELEMS (48 * PLANE_PX)
#define NT_MAIN 512
#define NBANDS 32               // 16-row bands
#define NBLK (48 * NBANDS)      // 1536 blocks
#define RSTR 528                // uint2 row stride: 16B/128B aligned

// 2*C1 and 2*C2 (the 0.25 scale factors cancel in num/den)
#define C1x2 2.0e-4f
#define C2x2 1.8e-3f

typedef _Float16 h2 __attribute__((ext_vector_type(2)));
typedef _Float16 h8 __attribute__((ext_vector_type(8)));
typedef float f32x4 __attribute__((ext_vector_type(4)));
typedef __fp16 fp16v2 __attribute__((ext_vector_type(2)));

// Packed f16 FMA (v_pk_fma_f16).
__device__ __forceinline__ h2 h2fma(_Float16 w, h2 v, h2 acc) {
    h2 wv = {w, w};
    return __builtin_elementwise_fma(wv, v, acc);
}
__device__ __forceinline__ unsigned int h2bits(h2 v) {
    union { h2 h; unsigned int u; } c; c.h = v; return c.u;
}
// v_cvt_pkrtz_f16_f32 returns __fp16x2; bit-cast to _Float16x2 (same layout).
__device__ __forceinline__ h2 pkrtz(float x, float y) {
    union { fp16v2 f; h2 h; } c;
    c.f = __builtin_amdgcn_cvt_pkrtz(x, y);
    return c.h;
}

__global__ void __launch_bounds__(NT_MAIN, 4) ssim_main(
    const float* __restrict__ img1, const float* __restrict__ img2,
    float* __restrict__ partials)
{
    // FULL-WIDTH 512-col x 16-row band, 512 threads (8 waves), 1 col/thread:
    // kills the horizontal staging/conv redundancy entirely (R5's 64/48) and
    // keeps R1's best vertical redundancy (26/16). Horizontal zero-padding
    // (reference semantics) via 8 zeroed pad-cols each side in LDS.
    // Packed f16: R[row][col] = {(cs,cd),(css,cdd)} uint2, logical col =
    // global col + 8. XOR swizzle (R5-verified): physical = logical ^
    // ((row&7)<<1) -> b128 reads 2-way bank-balanced, pairs stay contiguous.
    __shared__ __align__(16) uint2 R[16 * RSTR];   // 67,584 B -> 2 blocks/CU

    // Gaussian window (f16 taps for vertical conv).
    constexpr _Float16 Gh[11] = {
        (_Float16)0.00102838f, (_Float16)0.00759876f, (_Float16)0.03600077f,
        (_Float16)0.10936070f, (_Float16)0.21300553f, (_Float16)0.26601173f,
        (_Float16)0.21300553f, (_Float16)0.10936070f, (_Float16)0.03600077f,
        (_Float16)0.00759876f, (_Float16)0.00102838f
    };

    const int tid = threadIdx.x;
    const int lane = tid & 63;
    const int wv = tid >> 6;                     // wave [0,8)

    // Work decode + XCD swizzle: XCD (blockIdx&7) owns 6 contiguous planes.
    const int xcd = blockIdx.x & 7;
    const int idx = blockIdx.x >> 3;             // [0,192)
    const int pl = xcd * 6 + idx / NBANDS;
    const int band = idx & (NBANDS - 1);
    const int ty0 = band * 16;
    const float* pa = img1 + (size_t)pl * PLANE_PX;
    const float* pb = img2 + (size_t)pl * PLANE_PX;

    // Zero the pad columns (logical 0..7 and 520..527, swizzled per row).
    if (tid < 16) {
        const int s = (tid & 7) << 1;
        uint2* row = R + tid * RSTR;
#pragma unroll
        for (int k = 0; k < 8; ++k) {
            row[k ^ s] = make_uint2(0u, 0u);
            row[(520 + k) ^ s] = make_uint2(0u, 0u);
        }
    }

    // ================= Phase A: vertical conv, thread = column ==============
    // Each thread stages 26 rows of its column (coalesced across threads),
    // computes 16 output rows via the sliding 11-tap conv (pk_fma, 2 signals
    // per inst), writes 16 uint2 to LDS.
    const int c = tid;                           // global col [0,512)
    const int ry0 = ty0 - 5;
    float av[26], bv[26];
    const bool intY = (ry0 >= 0) && (ry0 + 26 <= IMG_H);     // block-uniform
    if (intY) {
        const float* qa = pa + (size_t)ry0 * IMG_W + c;
        const float* qb = pb + (size_t)ry0 * IMG_W + c;
#pragma unroll
        for (int j = 0; j < 26; ++j) {
            av[j] = qa[j * IMG_W];
            bv[j] = qb[j * IMG_W];
        }
    } else {
#pragma unroll
        for (int j = 0; j < 26; ++j) {
            int ry = ry0 + j;
            int ryc = min(max(ry, 0), IMG_H - 1);
            float rm = ((unsigned)ry < (unsigned)IMG_H) ? 1.f : 0.f;
            av[j] = pa[(size_t)ryc * IMG_W + c] * rm;
            bv[j] = pb[(size_t)ryc * IMG_W + c] * rm;
        }
    }

    h2 asd[16], asq[16];
#pragma unroll
    for (int k = 0; k < 16; ++k) { asd[k] = (h2)(_Float16)0; asq[k] = (h2)(_Float16)0; }
#pragma unroll
    for (int j = 0; j < 26; ++j) {
        // (s,d) packed to f16 in ONE inst (v_cvt_pkrtz_f16_f32).
        h2 sd = pkrtz(av[j] + bv[j], av[j] - bv[j]);
        h2 sq = sd * sd;                         // v_pk_mul_f16
#pragma unroll
        for (int k = 0; k < 16; ++k) {
            int tt = j - k;
            if (tt >= 0 && tt < 11) {            // folds at compile time
                asd[k] = h2fma(Gh[tt], sd, asd[k]);
                asq[k] = h2fma(Gh[tt], sq, asq[k]);
            }
        }
    }
#pragma unroll
    for (int k = 0; k < 16; ++k) {
        const int sc = (8 + c) ^ ((k & 7) << 1); // swizzled physical col
        R[k * RSTR + sc] = make_uint2(h2bits(asd[k]), h2bits(asq[k]));
    }
    __syncthreads();

    // ================= Phase B: horizontal conv via MFMA + SSIM =============
    // D[m][n] = sum_k A[m][k]*B[k][n], one mfma_f32_16x16x32_f16 per signal:
    //   m = out col in 16-group, k = staged col in 32-window, n = row.
    // Window base = logical LDS col ox0 (global ox0-8 via pads), so
    // A[m][k] = G[k-m-3], k-m-3 in [0,10] (R4-verified afh fragment).
    // A (lane l): m = l&15, k = (l>>4)*8 + j  -> constant band frag.
    // B (lane l): n = l&15, k = (l>>4)*8 + j  -> 4x ds_read_b128.
    // All 512x16 outputs valid: zero masks.
    const int nrow = lane & 15;
    const int khi = lane >> 4;
    const int swz = (nrow & 7) << 1;
    const uint2* Rrow = R + nrow * RSTR;

    // Gaussian band A-fragment (symmetric-tap select + 8 shuffles; lanes
    // >= 11 hold 0 so out-of-band taps are 0).
    int sidx = min(lane, 10 - lane);             // < 0 for lane > 10
    unsigned gvb = 0u;
    gvb = (sidx == 0) ? 0x1436u : gvb;           // f16 bits of G[0]
    gvb = (sidx == 1) ? 0x1FC8u : gvb;
    gvb = (sidx == 2) ? 0x289Cu : gvb;
    gvb = (sidx == 3) ? 0x2F00u : gvb;
    gvb = (sidx == 4) ? 0x32D1u : gvb;
    gvb = (sidx == 5) ? 0x3442u : gvb;           // f16 bits of G[5]
    union { h8 h; unsigned u[4]; } af;
#pragma unroll
    for (int w = 0; w < 4; ++w) {
        int t0 = khi * 8 + 2 * w - nrow;
        unsigned lo = (unsigned)__shfl((int)gvb, (t0 - 3) & 63, 64);
        unsigned hi = (unsigned)__shfl((int)gvb, (t0 - 2) & 63, 64);
        af.u[w] = (lo & 0xFFFFu) | (hi << 16);
    }

    const f32x4 z = {0.f, 0.f, 0.f, 0.f};
    float local = 0.f;
#pragma unroll
    for (int ii = 0; ii < 4; ++ii) {
        const int ox0 = (wv * 4 + ii) * 16;      // out-col group [0,512) st 16
        const int cb = ox0 + khi * 8;            // logical window col (even)
        const uint4 q0 = *(const uint4*)&Rrow[(cb + 0) ^ swz];
        const uint4 q1 = *(const uint4*)&Rrow[(cb + 2) ^ swz];
        const uint4 q2 = *(const uint4*)&Rrow[(cb + 4) ^ swz];
        const uint4 q3 = *(const uint4*)&Rrow[(cb + 6) ^ swz];

        // De-interleave packed {(s,d),(ss,dd)} into 4 per-signal frags.
        union { h8 h; unsigned u[4]; } fs, fd, fss, fdd;
        fs.u[0]  = (q0.x & 0xFFFFu) | (q0.z << 16);
        fs.u[1]  = (q1.x & 0xFFFFu) | (q1.z << 16);
        fs.u[2]  = (q2.x & 0xFFFFu) | (q2.z << 16);
        fs.u[3]  = (q3.x & 0xFFFFu) | (q3.z << 16);
        fd.u[0]  = (q0.x >> 16) | (q0.z & 0xFFFF0000u);
        fd.u[1]  = (q1.x >> 16) | (q1.z & 0xFFFF0000u);
        fd.u[2]  = (q2.x >> 16) | (q2.z & 0xFFFF0000u);
        fd.u[3]  = (q3.x >> 16) | (q3.z & 0xFFFF0000u);
        fss.u[0] = (q0.y & 0xFFFFu) | (q0.w << 16);
        fss.u[1] = (q1.y & 0xFFFFu) | (q1.w << 16);
        fss.u[2] = (q2.y & 0xFFFFu) | (q2.w << 16);
        fss.u[3] = (q3.y & 0xFFFFu) | (q3.w << 16);
        fdd.u[0] = (q0.y >> 16) | (q0.w & 0xFFFF0000u);
        fdd.u[1] = (q1.y >> 16) | (q1.w & 0xFFFF0000u);
        fdd.u[2] = (q2.y >> 16) | (q2.w & 0xFFFF0000u);
        fdd.u[3] = (q3.y >> 16) | (q3.w & 0xFFFF0000u);

        f32x4 aS  = __builtin_amdgcn_mfma_f32_16x16x32_f16(af.h, fs.h,  z, 0, 0, 0);
        f32x4 aD  = __builtin_amdgcn_mfma_f32_16x16x32_f16(af.h, fd.h,  z, 0, 0, 0);
        f32x4 aSS = __builtin_amdgcn_mfma_f32_16x16x32_f16(af.h, fss.h, z, 0, 0, 0);
        f32x4 aDD = __builtin_amdgcn_mfma_f32_16x16x32_f16(af.h, fdd.h, z, 0, 0, 0);

        // num/den share the 0.25 factor -> cancelled; constants are 2*C.
#pragma unroll
        for (int i = 0; i < 4; ++i) {
            float cs = aS[i], cd = aD[i], css = aSS[i], cdd = aDD[i];
            float Pq = cs * cs, Qq = cd * cd;
            float U = Pq - Qq;                   // 4*mu1*mu2
            float V = Pq + Qq;                   // 2*(mu1^2+mu2^2)
            float num = (U + C1x2) * ((css - cdd) - U + C2x2);
            float den = (V + C1x2) * ((css + cdd) - V + C2x2);
            local += num * __builtin_amdgcn_rcpf(den);
        }
    }

    // ================= Block reduction -> one partial ========================
#pragma unroll
    for (int off = 32; off > 0; off >>= 1) local += __shfl_down(local, off, 64);
    __syncthreads();                             // all R reads done: safe alias
    float* wp = (float*)R;
    if (lane == 0) wp[wv] = local;
    __syncthreads();
    if (tid == 0) {
        float s = 0.f;
#pragma unroll
        for (int w = 0; w < 8; ++w) s += wp[w];
        partials[blockIdx.x] = s;
    }
}

__global__ void ssim_final(const float* __restrict__ partials,
                           float* __restrict__ out)
{
    __shared__ float wp[4];
    const int tid = threadIdx.x;
    const float4* p4 = (const float4*)partials;  // 1536/4 = 384 float4
    float s = 0.f;
    for (int i = tid; i < NBLK / 4; i += 256) {
        float4 v = p4[i];
        s += (v.x + v.y) + (v.z + v.w);
    }
#pragma unroll
    for (int off = 32; off > 0; off >>= 1) s += __shfl_down(s, off, 64);
    if ((tid & 63) == 0) wp[tid >> 6] = s;
    __syncthreads();
    if (tid == 0)
        out[0] = 1.0f - (wp[0] + wp[1] + wp[2] + wp[3]) * (1.0f / (float)N_ELEMS);
}

extern "C" void kernel_launch(void* const* d_in, const int* in_sizes, int n_in,
                              void* d_out, int out_size, void* d_ws, size_t ws_size,
                              hipStream_t stream) {
    const float* img1 = (const float*)d_in[0];
    const float* img2 = (const float*)d_in[1];
    float* out = (float*)d_out;
    float* partials = (float*)d_ws;     // NBLK floats = 6.1 KB

    ssim_main<<<NBLK, NT_MAIN, 0, stream>>>(img1, img2, partials);
    ssim_final<<<1, 256, 0, stream>>>(partials, out);
}